// Round 12
// baseline (106.572 us; speedup 1.0000x reference)
//
#include <hip/hip_runtime.h>

#define T_GT 64
#define KP 4            // priors per thread, strided by TPB within the block
#define TPB 256
#define NB 64           // screen bins per axis (1/64 exact pow2)
#define CAP 768         // candidate records per wave per k (overflow -> fallback)

typedef unsigned int u32;
typedef unsigned long long u64;

// ---------------------------------------------------------------------------
// Round-12: wave-pooled candidate redistribution (attack max-vs-mean).
//
// r4/r10/r11 post-mortems: VALU cuts, conflict cuts, 2-deep pipeline all
// flat; only work-count cuts (r5 screen) moved time. Remaining 3x gap vs
// throughput floor == divergence inflation: priors are spatially RANDOM,
// so lane masks are uncorrelated; while(mask) costs the wave max popcount
// (~9) though the mean is ~2.5. Sum over KP=4: ~36 serialized iters of
// ~10 of real work.
//
// Fix: per k, redistribute the wave's candidates evenly:
//  - stage each lane's prior (5xB32) in per-wave LDS slots;
//  - __shfl_up prefix-sum of popcounts -> global slot per candidate;
//  - lanes write u16 records (lane<<6)|t into a per-wave pool;
//  - UNIFORM loop (trip = ceil(C/64), C wave-uniform): each lane processes
//    one record/iter: SoA gt reads + owner-prior reads, q, then
//    atomicMax s_best[wv][t] (col argmax, unchanged packing) and
//    atomicMax s_pbest[wv][owner] (row argmax, == old mbest packing).
//  - records capped at CAP; leftover mask bits (P~0) run the old
//    divergent loop -> correctness never data-dependent.
// All shfls in full-exec regions (r8 lesson). Same-wave LDS ordering +
// compiler lgkmcnt make pool writes/atomics visible to later reads.
//
// Kept (proven): ballot screen tables (superset of inter>0; q=0 loses to
// defaults exactly); guard-free pow2 bins; hoisted prk[] loads; clamped
// dup-of-P-1 participation (ties harmless, stores guarded); SoA gt;
// bit-exact __f*_rn IoU with IEEE __fdiv_rn in the argmax path; cheap
// native math in the epilogue only; two-kernel split w/ plain stores.
//
// Invariants (r1-r11):
//  match: pack (q<<32)|(63-t) max (63-t: first-index tie-break);
//  best_prior: LDS atomicMax (q<<32)|(0xFFFFFFFF - p) per wave per t;
//  defaults {q=0,t=0}/{q=0,p=0} == numpy argmax over all-zero rows/cols.
// ---------------------------------------------------------------------------
__global__ void __launch_bounds__(256)
match_main(const float4* __restrict__ priors,
           const float4* __restrict__ gt_boxes,
           const int* __restrict__ gt_labels,
           u64* __restrict__ part,        // (B, NG, 64) block partials
           float* __restrict__ out_loc,   // (B, P, 4)
           float* __restrict__ out_lbl,   // (B, P) as float
           int P, int NG) {
    __shared__ float s_gx0[T_GT], s_gy0[T_GT], s_gx1[T_GT], s_gy1[T_GT];
    __shared__ int   s_lbl[T_GT];
    __shared__ u64   s_best[4][T_GT];
    __shared__ u64   s_tab[4][NB];
    __shared__ float s_px0[4][64], s_py0[4][64], s_px1[4][64], s_py1[4][64];
    __shared__ u32   s_pp[4][64];
    __shared__ u64   s_pbest[4][64];
    __shared__ unsigned short s_cand[4][CAP];

    const int tid  = threadIdx.x;
    const int lane = tid & 63;
    const int wv   = tid >> 6;
    const int b    = blockIdx.y;
    const int pbase = blockIdx.x * (TPB * KP);

    // every wave holds gt[lane] in registers (ballot source)
    const float4 gb = gt_boxes[b * T_GT + lane];

    if (wv == 0) {                      // wave 0 seeds SoA gt + labels
        s_gx0[lane] = gb.x;
        s_gy0[lane] = gb.y;
        s_gx1[lane] = gb.z;
        s_gy1[lane] = gb.w;
        s_lbl[lane] = gt_labels[b * T_GT + lane];
    }
    s_best[wv][lane] = (u64)0xFFFFFFFFu;   // {q=+0.0, p=0} default

    // ---- ballot table build: wave = axis, bit of ballot = lane = t ----
    if (wv == 0) {
        #pragma unroll 8
        for (int bin = 0; bin < NB; ++bin) {
            const u64 m = __ballot(gb.z > (float)bin * (1.0f / NB));
            if (lane == 0) s_tab[0][bin] = m;
        }
    } else if (wv == 1) {
        #pragma unroll 8
        for (int bin = 0; bin < NB; ++bin) {
            const u64 m = __ballot(gb.x < (float)(bin + 1) * (1.0f / NB));
            if (lane == 0) s_tab[1][bin] = m;
        }
    } else if (wv == 2) {
        #pragma unroll 8
        for (int bin = 0; bin < NB; ++bin) {
            const u64 m = __ballot(gb.w > (float)bin * (1.0f / NB));
            if (lane == 0) s_tab[2][bin] = m;
        }
    } else {
        #pragma unroll 8
        for (int bin = 0; bin < NB; ++bin) {
            const u64 m = __ballot(gb.y < (float)(bin + 1) * (1.0f / NB));
            if (lane == 0) s_tab[3][bin] = m;
        }
    }

    // hoisted prior loads: 4 independent VMEM issues, one wait
    float4 prk[KP];
    #pragma unroll
    for (int k = 0; k < KP; ++k)
        prk[k] = priors[min(pbase + k * TPB + tid, P - 1)];

    __syncthreads();

    // ---- per-prior loop: stage -> pool -> uniform eval -> epilogue ----
    #pragma unroll
    for (int k = 0; k < KP; ++k) {
        const int p  = pbase + k * TPB + tid;   // strided: coalesced ST
        const int pe = min(p, P - 1);
        const float4 pr = prk[k];
        const float px0 = __fsub_rn(pr.x, __fmul_rn(0.5f, pr.z));
        const float py0 = __fsub_rn(pr.y, __fmul_rn(0.5f, pr.w));
        const float px1 = __fadd_rn(pr.x, __fmul_rn(0.5f, pr.z));
        const float py1 = __fadd_rn(pr.y, __fmul_rn(0.5f, pr.w));
        const float pa  = __fmul_rn(__fsub_rn(px1, px0),
                                    __fsub_rn(py1, py0));

        // guard-free bins: px*NB exact (pow2), _rd == floor
        const int bx0 = min(max(__float2int_rd(px0 * (float)NB), 0), NB - 1);
        const int bx1 = min(max(__float2int_rd(px1 * (float)NB), 0), NB - 1);
        const int by0 = min(max(__float2int_rd(py0 * (float)NB), 0), NB - 1);
        const int by1 = min(max(__float2int_rd(py1 * (float)NB), 0), NB - 1);

        const u64 mask = s_tab[0][bx0] & s_tab[1][bx1] &
                         s_tab[2][by0] & s_tab[3][by1];  // superset inter>0

        // stage this lane's prior in the wave's LDS slots
        s_px0[wv][lane] = px0;
        s_py0[wv][lane] = py0;
        s_px1[wv][lane] = px1;
        s_py1[wv][lane] = py1;
        s_pp [wv][lane] = (u32)pe;
        s_pbest[wv][lane] = 63u;        // {q=0, rt=63} == t 0 default

        // prefix-sum of candidate counts (full exec -> shfl defined)
        const int cnt = (int)__builtin_popcountll(mask);
        int inc = cnt;
        #pragma unroll
        for (int d = 1; d < 64; d <<= 1) {
            const int v = __shfl_up(inc, d, 64);
            if (lane >= d) inc += v;
        }
        const int excl = inc - cnt;
        const int C    = __shfl(inc, 63, 64);   // wave-uniform total

        // write compact records (divergent, capped; leftover -> fallback)
        u64 mrem = mask;
        int off  = excl;
        while (mrem && off < CAP) {
            const int t = (int)__builtin_ctzll(mrem);
            mrem &= mrem - 1;
            s_cand[wv][off++] = (unsigned short)((lane << 6) | t);
        }

        // ---- uniform pooled evaluation: trip count is wave-uniform ----
        const int Cc = (C < CAP) ? C : CAP;
        const int iters = (Cc + 63) >> 6;
        int j   = lane;
        u32 rec = (j < Cc) ? (u32)s_cand[wv][j] : 0u;
        for (int it = 0; it < iters; ++it) {
            const bool act = (j < Cc);
            const int  jn  = j + 64;
            const u32  recn = (jn < Cc) ? (u32)s_cand[wv][jn] : 0u; // prefetch
            const int o = (int)(rec >> 6) & 63;
            const int t = (int)(rec & 63u);
            const float gx0 = s_gx0[t], gy0 = s_gy0[t];
            const float gx1 = s_gx1[t], gy1 = s_gy1[t];
            const float qx0 = s_px0[wv][o], qy0 = s_py0[wv][o];
            const float qx1 = s_px1[wv][o], qy1 = s_py1[wv][o];
            const u32   po  = s_pp[wv][o];
            // bit-exact recompute (same __f*_rn ops as originals)
            const float qa  = __fmul_rn(__fsub_rn(qx1, qx0),
                                        __fsub_rn(qy1, qy0));
            const float gar = __fmul_rn(__fsub_rn(gx1, gx0),
                                        __fsub_rn(gy1, gy0));
            const float wx = fmaxf(__fsub_rn(fminf(gx1, qx1),
                                             fmaxf(gx0, qx0)), 0.0f);
            const float wy = fmaxf(__fsub_rn(fminf(gy1, qy1),
                                             fmaxf(gy0, qy0)), 0.0f);
            const float inter = __fmul_rn(wx, wy);
            if (act && inter > 0.0f) {
                const float uni = __fsub_rn(__fadd_rn(gar, qa), inter);
                const float q = __fdiv_rn(inter, uni);  // IEEE: argmax order
                const u64 qh = (u64)__float_as_uint(q) << 32;
                atomicMax(&s_best[wv][t], qh | (u64)(0xFFFFFFFFu - po));
                atomicMax(&s_pbest[wv][o], qh | (u64)(u32)(63 - t));
            }
            rec = recn; j = jn;
        }

        // ---- divergent fallback for capped leftovers (P ~ 0) ----
        u64 mbest = 63u;
        while (mrem) {
            const int t = (int)__builtin_ctzll(mrem);
            mrem &= mrem - 1;
            const float gx0 = s_gx0[t], gy0 = s_gy0[t];
            const float gx1 = s_gx1[t], gy1 = s_gy1[t];
            const float gar = __fmul_rn(__fsub_rn(gx1, gx0),
                                        __fsub_rn(gy1, gy0));
            const float wx = fmaxf(__fsub_rn(fminf(gx1, px1),
                                             fmaxf(gx0, px0)), 0.0f);
            const float wy = fmaxf(__fsub_rn(fminf(gy1, py1),
                                             fmaxf(gy0, py0)), 0.0f);
            const float inter = __fmul_rn(wx, wy);
            if (inter > 0.0f) {
                const float uni = __fsub_rn(__fadd_rn(gar, pa), inter);
                const float q = __fdiv_rn(inter, uni);
                const u64 qh = (u64)__float_as_uint(q) << 32;
                const u64 mp = qh | (u32)(63 - t);
                if (mp > mbest) mbest = mp;
                atomicMax(&s_best[wv][t], qh | (u64)(0xFFFFFFFFu - (u32)pe));
            }
        }

        // combine pooled + fallback row-best (compiler lgkmcnt covers the
        // wave's own atomic instructions -> all lanes' contributions done)
        {
            const u64 v = s_pbest[wv][lane];
            if (v > mbest) mbest = v;
        }

        // epilogue: cheap native math (not in argmax path)
        const int   t_best = 63 - (int)(mbest & 63u);
        const float q_best = __uint_as_float((u32)(mbest >> 32));
        const int   lbl = (q_best < 0.5f) ? 0 : s_lbl[t_best];

        const float mx0 = s_gx0[t_best];
        const float my0 = s_gy0[t_best];
        const float mx1 = s_gx1[t_best];
        const float my1 = s_gy1[t_best];

        const float bcx = (mx0 + mx1) * 0.5f;
        const float bcy = (my0 + my1) * 0.5f;
        const float bw  = mx1 - mx0;
        const float bh  = my1 - my0;

        const float lx = __fdividef(bcx - pr.x, 0.1f * pr.z);
        const float ly = __fdividef(bcy - pr.y, 0.1f * pr.w);
        const float lz = __logf(__fdividef(bw, pr.z)) * 5.0f;
        const float lw = __logf(__fdividef(bh, pr.w)) * 5.0f;

        if (p < P) {
            float4* rowp = (float4*)(out_loc + ((size_t)b * P + p) * 4);
            *rowp = make_float4(lx, ly, lz, lw);
            out_lbl[(size_t)b * P + p] = (float)lbl;
        }
    }

    __syncthreads();
    if (tid < T_GT) {
        u64 m = s_best[0][tid];
        #pragma unroll
        for (int w = 1; w < 4; ++w) {
            const u64 v = s_best[w][tid];
            if (v > m) m = v;
        }
        part[((size_t)b * NG + blockIdx.x) * T_GT + tid] = m;   // plain store
    }
}

// ---------------------------------------------------------------------------
// Finisher: one block per image. Reduce NG partials per t, apply
// matches[best_prior[t]] = t (ascending-scan dedupe = numpy last-wins).
// ---------------------------------------------------------------------------
__global__ void __launch_bounds__(256)
match_fin(const float4* __restrict__ priors,
          const float4* __restrict__ gt_boxes,
          const int* __restrict__ gt_labels,
          const u64* __restrict__ part,
          float* __restrict__ out_loc,
          float* __restrict__ out_lbl,
          int P, int NG) {
    __shared__ float4 s_gt[T_GT];
    __shared__ int    s_lbl[T_GT];
    __shared__ u64    s_best[4][T_GT];
    __shared__ u32    s_p[T_GT];

    const int tid = threadIdx.x;
    const int b   = blockIdx.x;
    const int t   = tid & 63;
    const int w   = tid >> 6;

    if (tid < T_GT) {
        s_gt[tid]  = gt_boxes[b * T_GT + tid];
        s_lbl[tid] = gt_labels[b * T_GT + tid];
    }

    const size_t base = (size_t)b * NG * T_GT + t;
    u64 m = 0;
    int g = w;
    for (; g + 12 < NG; g += 16) {      // 4 independent loads in flight
        const u64 a0 = part[base + (size_t)g * T_GT];
        const u64 a1 = part[base + (size_t)(g + 4) * T_GT];
        const u64 a2 = part[base + (size_t)(g + 8) * T_GT];
        const u64 a3 = part[base + (size_t)(g + 12) * T_GT];
        u64 x = a0 > a1 ? a0 : a1;
        const u64 y = a2 > a3 ? a2 : a3;
        if (y > x) x = y;
        if (x > m) m = x;
    }
    for (; g < NG; g += 4) {
        const u64 v = part[base + (size_t)g * T_GT];
        if (v > m) m = v;
    }
    s_best[w][t] = m;
    __syncthreads();
    if (tid < T_GT) {
        m = s_best[0][t];
        #pragma unroll
        for (int i = 1; i < 4; ++i) {
            const u64 v = s_best[i][t];
            if (v > m) m = v;
        }
        s_p[t] = 0xFFFFFFFFu - (u32)(m & 0xFFFFFFFFull);
    }
    __syncthreads();
    if (tid >= T_GT) return;

    // matches[best_prior] = arange(T): numpy last-wins on duplicates
    const u32 p = s_p[tid];
    for (int u = tid + 1; u < T_GT; ++u)
        if (s_p[u] == p) return;

    const float4 pr = priors[p];
    const float4 mb = s_gt[tid];
    const float  bcx = (mb.x + mb.z) * 0.5f;
    const float  bcy = (mb.y + mb.w) * 0.5f;
    const float  bw  = mb.z - mb.x;
    const float  bh  = mb.w - mb.y;

    const float lx = __fdividef(bcx - pr.x, 0.1f * pr.z);
    const float ly = __fdividef(bcy - pr.y, 0.1f * pr.w);
    const float lz = __logf(__fdividef(bw, pr.z)) * 5.0f;
    const float lw = __logf(__fdividef(bh, pr.w)) * 5.0f;

    float4* rowp = (float4*)(out_loc + ((size_t)b * P + p) * 4);
    *rowp = make_float4(lx, ly, lz, lw);
    out_lbl[(size_t)b * P + p] = (float)s_lbl[tid];
}

extern "C" void kernel_launch(void* const* d_in, const int* in_sizes, int n_in,
                              void* d_out, int out_size, void* d_ws, size_t ws_size,
                              hipStream_t stream) {
    const float4* priors    = (const float4*)d_in[0];   // (P, 4) f32
    const float4* gt_boxes  = (const float4*)d_in[1];   // (B, T, 4) f32
    const int*    gt_labels = (const int*)d_in[2];      // (B, T) i32

    const int P = in_sizes[0] / 4;
    const int B = in_sizes[2] / T_GT;

    float* out_loc = (float*)d_out;
    float* out_lbl = out_loc + (size_t)B * P * 4;

    const int NG = (P + TPB * KP - 1) / (TPB * KP);   // blocks per image (98)
    u64* part = (u64*)d_ws;                            // (B, NG, 64) u64

    dim3 g(NG, B);
    match_main<<<g, TPB, 0, stream>>>(priors, gt_boxes, gt_labels, part,
                                      out_loc, out_lbl, P, NG);
    match_fin<<<dim3(B), TPB, 0, stream>>>(priors, gt_boxes, gt_labels, part,
                                           out_loc, out_lbl, P, NG);
}

// Round 13
// 101.124 us; speedup vs baseline: 1.0539x; 1.0539x over previous
//
#include <hip/hip_runtime.h>

#define T_GT 64
#define KP 4            // priors per thread, strided by TPB within the block
#define TPB 256
#define NB 64           // screen bins per axis (1/64 exact pow2)

typedef unsigned int u32;
typedef unsigned long long u64;

// ---------------------------------------------------------------------------
// Round-13: REVERT to round-7 exactly -- the session's measured best
// (bench 101.1 us; main ~33 us). Rounds 8-12 tested five orthogonal
// theories of main's remaining cost (crossbar shfl, SoA bank conflicts,
// 2-deep LDS pipeline, hoisted VMEM, wave-pooled divergence removal):
// all flat or regressed. Work-elimination (r5 screen, r7 fusion) were the
// only wins. Locking in the best-known structure.
//
// Structure (r7): per-prior fused loop + strided ownership + cheap
// epilogue math.
//  (1) Strided ownership p = blk*1024 + k*256 + tid: all prior loads and
//      output stores perfectly coalesced per instruction.
//  (2) Guard-free bins: px*64 is EXACT (pow2 mul), __float2int_rd == floor
//      -> bin/64 <= px0 and px1 < (bin+1)/64 by construction (superset
//      preserved; clamps at 0/63 only loosen).
//  (3) Epilogue: __logf (native v_log) + __fdividef (rcp+mul). Abs error
//      ~1e-5 on outputs -- far inside tolerance. Phase-2 q KEEPS __fdiv_rn
//      (feeds argmax ordering; must match jax bit-exactly).
//  (4) Per-k fused body (setup->screen->phase2->epilogue): one prior's
//      state live at a time -> minimal VGPR.
//  (5) OOB tail threads (p >= P) skip entirely.
//
// Screen (r5-r7, verified): SUPERSET of inter>0 is sufficient:
// phase-2 yields q=+0.0 for non-overlapping candidates and the packings
// (q<<32)|(63-t) / (q<<32)|(~p) make q=0 lose to the defaults exactly.
// Tables: T0[i]={t: gb.z > i/NB}, T1[i]={t: gb.x < (i+1)/NB}, T2/T3 for y.
//
// Two-kernel split (r3, verified): main kernel plain cached stores
// (L2 write-back merges sectors); finisher applies matches[best_prior[t]]=t.
// Kernel-boundary ordering = visibility.
//
// Invariants (r1-r12):
//  match: pack (q<<32)|(63-t) max (63-t: first-index tie-break);
//  best_prior: LDS atomicMax (q<<32)|(0xFFFFFFFF - p) per wave per t;
//  defaults == numpy argmax over implicit all-zero rows/cols.
// ---------------------------------------------------------------------------
__global__ void __launch_bounds__(256)
match_main(const float4* __restrict__ priors,
           const float4* __restrict__ gt_boxes,
           const int* __restrict__ gt_labels,
           u64* __restrict__ part,        // (B, NG, 64) block partials
           float* __restrict__ out_loc,   // (B, P, 4)
           float* __restrict__ out_lbl,   // (B, P) as float
           int P, int NG) {
    __shared__ float4 s_gt[T_GT];
    __shared__ float  s_ga[T_GT];
    __shared__ int    s_lbl[T_GT];
    __shared__ u64    s_best[4][T_GT];
    __shared__ u64    s_tab[4][NB];

    const int tid  = threadIdx.x;
    const int lane = tid & 63;
    const int wv   = tid >> 6;
    const int b    = blockIdx.y;
    const int pbase = blockIdx.x * (TPB * KP);

    if (tid < T_GT) {
        const float4 gb = gt_boxes[b * T_GT + tid];
        s_gt[tid]  = gb;
        s_ga[tid]  = __fmul_rn(__fsub_rn(gb.z, gb.x), __fsub_rn(gb.w, gb.y));
        s_lbl[tid] = gt_labels[b * T_GT + tid];
    }
    s_best[wv][lane] = (u64)0xFFFFFFFFu;   // {q=+0.0, p=0} default
    __syncthreads();

    // ---- build threshold tables: wave = table, lane = bin ----
    {
        const float thL = (float)lane * (1.0f / NB);    // exact
        const float thR = thL + (1.0f / NB);            // exact
        u64 m = 0;
        if (wv == 0) {
            #pragma unroll 8
            for (int t = T_GT - 1; t >= 0; --t)
                m = m + m + ((s_gt[t].z > thL) ? 1u : 0u);
        } else if (wv == 1) {
            #pragma unroll 8
            for (int t = T_GT - 1; t >= 0; --t)
                m = m + m + ((s_gt[t].x < thR) ? 1u : 0u);
        } else if (wv == 2) {
            #pragma unroll 8
            for (int t = T_GT - 1; t >= 0; --t)
                m = m + m + ((s_gt[t].w > thL) ? 1u : 0u);
        } else {
            #pragma unroll 8
            for (int t = T_GT - 1; t >= 0; --t)
                m = m + m + ((s_gt[t].y < thR) ? 1u : 0u);
        }
        s_tab[wv][lane] = m;
    }
    __syncthreads();

    // ---- per-prior fused loop: setup -> screen -> phase2 -> epilogue ----
    #pragma unroll
    for (int k = 0; k < KP; ++k) {
        const int p = pbase + k * TPB + tid;    // strided: coalesced LD/ST
        if (p < P) {
            const float4 pr = priors[p];
            const float px0 = __fsub_rn(pr.x, __fmul_rn(0.5f, pr.z));
            const float py0 = __fsub_rn(pr.y, __fmul_rn(0.5f, pr.w));
            const float px1 = __fadd_rn(pr.x, __fmul_rn(0.5f, pr.z));
            const float py1 = __fadd_rn(pr.y, __fmul_rn(0.5f, pr.w));
            const float pa  = __fmul_rn(__fsub_rn(px1, px0),
                                        __fsub_rn(py1, py0));

            // guard-free bins: px*NB exact (pow2), _rd == floor
            const int bx0 = min(max(__float2int_rd(px0 * (float)NB), 0), NB - 1);
            const int bx1 = min(max(__float2int_rd(px1 * (float)NB), 0), NB - 1);
            const int by0 = min(max(__float2int_rd(py0 * (float)NB), 0), NB - 1);
            const int by1 = min(max(__float2int_rd(py1 * (float)NB), 0), NB - 1);

            u64 mask = s_tab[0][bx0] & s_tab[1][bx1] &
                       s_tab[2][by0] & s_tab[3][by1];   // superset of inter>0

            u64 mbest = 63u;                  // {q=0, rt=63} == t 0
            while (mask) {                    // ascending t per lane
                const int t = (int)__builtin_ctzll(mask);
                mask &= mask - 1;
                const float4 gb  = s_gt[t];
                const float  gar = s_ga[t];
                const float ltx = fmaxf(gb.x, px0);
                const float lty = fmaxf(gb.y, py0);
                const float rbx = fminf(gb.z, px1);
                const float rby = fminf(gb.w, py1);
                const float wx = fmaxf(__fsub_rn(rbx, ltx), 0.0f);
                const float wy = fmaxf(__fsub_rn(rby, lty), 0.0f);
                const float inter = __fmul_rn(wx, wy);
                const float uni = __fsub_rn(__fadd_rn(gar, pa), inter);
                const float q = __fdiv_rn(inter, uni);  // IEEE: argmax order
                const u64 qh = (u64)__float_as_uint(q) << 32;
                const u64 mp = qh | (u32)(63 - t);
                if (mp > mbest) mbest = mp;
                atomicMax(&s_best[wv][t], qh | (u64)(0xFFFFFFFFu - (u32)p));
            }

            // epilogue: native log/div (tolerance-safe; not in argmax path)
            const int   t_best = 63 - (int)(mbest & 63u);
            const float q_best = __uint_as_float((u32)(mbest >> 32));
            const int   lbl = (q_best < 0.5f) ? 0 : s_lbl[t_best];

            const float4 mb = s_gt[t_best];
            const float  bcx = (mb.x + mb.z) * 0.5f;
            const float  bcy = (mb.y + mb.w) * 0.5f;
            const float  bw  = mb.z - mb.x;
            const float  bh  = mb.w - mb.y;

            const float lx = __fdividef(bcx - pr.x, 0.1f * pr.z);
            const float ly = __fdividef(bcy - pr.y, 0.1f * pr.w);
            const float lz = __logf(__fdividef(bw, pr.z)) * 5.0f;
            const float lw = __logf(__fdividef(bh, pr.w)) * 5.0f;

            float4* rowp = (float4*)(out_loc + ((size_t)b * P + p) * 4);
            *rowp = make_float4(lx, ly, lz, lw);
            out_lbl[(size_t)b * P + p] = (float)lbl;
        }
    }

    __syncthreads();
    if (tid < T_GT) {
        u64 m = s_best[0][tid];
        #pragma unroll
        for (int w = 1; w < 4; ++w) {
            const u64 v = s_best[w][tid];
            if (v > m) m = v;
        }
        part[((size_t)b * NG + blockIdx.x) * T_GT + tid] = m;   // plain store
    }
}

// ---------------------------------------------------------------------------
// Finisher: one block per image. Reduce NG partials per t, apply
// matches[best_prior[t]] = t (ascending-scan dedupe = numpy last-wins).
// ---------------------------------------------------------------------------
__global__ void __launch_bounds__(256)
match_fin(const float4* __restrict__ priors,
          const float4* __restrict__ gt_boxes,
          const int* __restrict__ gt_labels,
          const u64* __restrict__ part,
          float* __restrict__ out_loc,
          float* __restrict__ out_lbl,
          int P, int NG) {
    __shared__ float4 s_gt[T_GT];
    __shared__ int    s_lbl[T_GT];
    __shared__ u64    s_best[4][T_GT];
    __shared__ u32    s_p[T_GT];

    const int tid = threadIdx.x;
    const int b   = blockIdx.x;
    const int t   = tid & 63;
    const int w   = tid >> 6;

    if (tid < T_GT) {
        s_gt[tid]  = gt_boxes[b * T_GT + tid];
        s_lbl[tid] = gt_labels[b * T_GT + tid];
    }

    const size_t base = (size_t)b * NG * T_GT + t;
    u64 m = 0;
    int g = w;
    for (; g + 12 < NG; g += 16) {      // 4 independent loads in flight
        const u64 a0 = part[base + (size_t)g * T_GT];
        const u64 a1 = part[base + (size_t)(g + 4) * T_GT];
        const u64 a2 = part[base + (size_t)(g + 8) * T_GT];
        const u64 a3 = part[base + (size_t)(g + 12) * T_GT];
        u64 x = a0 > a1 ? a0 : a1;
        const u64 y = a2 > a3 ? a2 : a3;
        if (y > x) x = y;
        if (x > m) m = x;
    }
    for (; g < NG; g += 4) {
        const u64 v = part[base + (size_t)g * T_GT];
        if (v > m) m = v;
    }
    s_best[w][t] = m;
    __syncthreads();
    if (tid < T_GT) {
        m = s_best[0][t];
        #pragma unroll
        for (int i = 1; i < 4; ++i) {
            const u64 v = s_best[i][t];
            if (v > m) m = v;
        }
        s_p[t] = 0xFFFFFFFFu - (u32)(m & 0xFFFFFFFFull);
    }
    __syncthreads();
    if (tid >= T_GT) return;

    // matches[best_prior] = arange(T): numpy last-wins on duplicates
    const u32 p = s_p[tid];
    for (int u = tid + 1; u < T_GT; ++u)
        if (s_p[u] == p) return;

    const float4 pr = priors[p];
    const float4 mb = s_gt[tid];
    const float  bcx = (mb.x + mb.z) * 0.5f;
    const float  bcy = (mb.y + mb.w) * 0.5f;
    const float  bw  = mb.z - mb.x;
    const float  bh  = mb.w - mb.y;

    const float lx = __fdividef(bcx - pr.x, 0.1f * pr.z);
    const float ly = __fdividef(bcy - pr.y, 0.1f * pr.w);
    const float lz = __logf(__fdividef(bw, pr.z)) * 5.0f;
    const float lw = __logf(__fdividef(bh, pr.w)) * 5.0f;

    float4* rowp = (float4*)(out_loc + ((size_t)b * P + p) * 4);
    *rowp = make_float4(lx, ly, lz, lw);
    out_lbl[(size_t)b * P + p] = (float)s_lbl[tid];
}

extern "C" void kernel_launch(void* const* d_in, const int* in_sizes, int n_in,
                              void* d_out, int out_size, void* d_ws, size_t ws_size,
                              hipStream_t stream) {
    const float4* priors    = (const float4*)d_in[0];   // (P, 4) f32
    const float4* gt_boxes  = (const float4*)d_in[1];   // (B, T, 4) f32
    const int*    gt_labels = (const int*)d_in[2];      // (B, T) i32

    const int P = in_sizes[0] / 4;
    const int B = in_sizes[2] / T_GT;

    float* out_loc = (float*)d_out;
    float* out_lbl = out_loc + (size_t)B * P * 4;

    const int NG = (P + TPB * KP - 1) / (TPB * KP);   // blocks per image (98)
    u64* part = (u64*)d_ws;                            // (B, NG, 64) u64

    dim3 g(NG, B);
    match_main<<<g, TPB, 0, stream>>>(priors, gt_boxes, gt_labels, part,
                                      out_loc, out_lbl, P, NG);
    match_fin<<<dim3(B), TPB, 0, stream>>>(priors, gt_boxes, gt_labels, part,
                                           out_loc, out_lbl, P, NG);
}